// Round 8
// baseline (504.001 us; speedup 1.0000x reference)
//
#include <hip/hip_runtime.h>
#include <hip/hip_bf16.h>
#include <stdint.h>

namespace {

constexpr int kB = 2;
constexpr int kN = 2048;
constexpr int kC = 1024;
constexpr int kH = 16;
constexpr int kD = 64;
constexpr int kTok = kB * kN;               // 4096
constexpr int k3C  = 3 * kC;                // 3072
constexpr size_t kPS = (size_t)kTok * k3C;  // qkv plane elems
constexpr size_t kXE = (size_t)kTok * kC;   // x / VT plane elems
constexpr size_t kWQ = (size_t)k3C * kC;    // qkv_w elems
constexpr size_t kWP = (size_t)kC * kC;     // proj_w elems

using bhalf8 = __attribute__((ext_vector_type(8))) __bf16;
using f32x4  = __attribute__((ext_vector_type(4))) float;

__device__ inline unsigned short f2bf(float f) {
  __hip_bfloat16 h = __float2bfloat16(f);
  return *reinterpret_cast<unsigned short*>(&h);
}
__device__ inline float bf2f(unsigned short u) {
  __hip_bfloat16 h;
  *reinterpret_cast<unsigned short*>(&h) = u;
  return __bfloat162float(h);
}
__device__ inline void split2(float v, unsigned short& h, unsigned short& l) {
  const unsigned short hb = f2bf(v);
  h = hb;
  l = f2bf(v - bf2f(hb));
}

// async global->LDS, 16B per lane; LDS dest must be wave-uniform base + lane*16
__device__ inline void glds16(const unsigned short* g, unsigned short* l) {
  __builtin_amdgcn_global_load_lds(
      (const __attribute__((address_space(1))) void*)g,
      (__attribute__((address_space(3))) void*)l, 16, 0, 0);
}

// ---- split fp32 -> bf16 hi/lo planes ----
__global__ __launch_bounds__(256)
void split_planes(const float* __restrict__ src,
                  unsigned short* __restrict__ H,
                  unsigned short* __restrict__ L, int n4)
{
  const int i = blockIdx.x * 256 + threadIdx.x;
  if (i >= n4) return;
  const float4 v = ((const float4*)src)[i];
  ushort4 hh, ll;
  split2(v.x, hh.x, ll.x); split2(v.y, hh.y, ll.y);
  split2(v.z, hh.z, ll.z); split2(v.w, hh.w, ll.w);
  ((ushort4*)H)[i] = hh;
  ((ushort4*)L)[i] = ll;
}

// ---- pre-transpose V slice of qkv planes into VT[bh][d][token] ----
__global__ __launch_bounds__(256)
void vt_transpose(const unsigned short* __restrict__ H,
                  const unsigned short* __restrict__ L,
                  unsigned short* __restrict__ VTH,
                  unsigned short* __restrict__ VTL)
{
  const int gw   = blockIdx.x * 4 + (threadIdx.x >> 6);  // 0..8191
  const int lane = threadIdx.x & 63;                     // = d
  const int bh   = gw >> 8;
  const int oct  = gw & 255;
  const int b = bh >> 4, h = bh & 15;
  const int tok0 = oct * 8;
  union { unsigned short u[8]; uint4 v; } ph, pl;
  #pragma unroll
  for (int e = 0; e < 8; ++e) {
    const size_t g = (size_t)(b * kN + tok0 + e) * k3C + 2 * kC + h * kD + lane;
    ph.u[e] = H[g];
    pl.u[e] = L[g];
  }
  const size_t o = ((size_t)bh * kD + lane) * kN + tok0;
  *(uint4*)(&VTH[o]) = ph.v;
  *(uint4*)(&VTL[o]) = pl.v;
}

// ---- plane GEMM: C = (AH+AL) @ (WH+WL)^T + bias; 3-term MFMA; m97 staging ----
template<bool OUTF32, bool FUSE_NORM>
__global__ __launch_bounds__(256)
void gemm_planes(const unsigned short* __restrict__ AH,
                 const unsigned short* __restrict__ AL, int lda,
                 const unsigned short* __restrict__ WH,
                 const unsigned short* __restrict__ WL,
                 const float* __restrict__ bias,
                 float* __restrict__ OutF,
                 unsigned short* __restrict__ OutH,
                 unsigned short* __restrict__ OutL,
                 const float* __restrict__ qn,
                 const float* __restrict__ kn,
                 int Nn, int K)
{
  __shared__ __align__(16) unsigned short AsH[128 * 32], AsL[128 * 32];
  __shared__ __align__(16) unsigned short BsH[128 * 32], BsL[128 * 32];

  const int t    = threadIdx.x;
  const int wave = t >> 6;
  const int lane = t & 63;
  const int quad = lane >> 4;
  const int l16  = lane & 15;
  const int bm = blockIdx.x * 128;
  const int bn = blockIdx.y * 128;
  const int wm = (wave >> 1) * 64;
  const int wn = (wave & 1) * 64;

  f32x4 acc[4][4] = {};

  for (int k0 = 0; k0 < K; k0 += 32) {
    #pragma unroll
    for (int r = 0; r < 2; ++r) {
      const int c   = r * 256 + t;
      const int row = c >> 2;
      const int col = (c & 3) * 8;
      glds16(&AH[(size_t)(bm + row) * lda + k0 + col], &AsH[c * 8]);
      glds16(&AL[(size_t)(bm + row) * lda + k0 + col], &AsL[c * 8]);
      glds16(&WH[(size_t)(bn + row) * K + k0 + col], &BsH[c * 8]);
      glds16(&WL[(size_t)(bn + row) * K + k0 + col], &BsL[c * 8]);
    }
    __syncthreads();

    bhalf8 afh[4], afl[4], bgh[4], bgl[4];
    #pragma unroll
    for (int i = 0; i < 4; ++i) {
      afh[i] = *(const bhalf8*)(&AsH[(wm + i * 16 + l16) * 32 + quad * 8]);
      afl[i] = *(const bhalf8*)(&AsL[(wm + i * 16 + l16) * 32 + quad * 8]);
      bgh[i] = *(const bhalf8*)(&BsH[(wn + i * 16 + l16) * 32 + quad * 8]);
      bgl[i] = *(const bhalf8*)(&BsL[(wn + i * 16 + l16) * 32 + quad * 8]);
    }
    #pragma unroll
    for (int i = 0; i < 4; ++i)
      #pragma unroll
      for (int j = 0; j < 4; ++j) {
        f32x4 a = acc[i][j];
        a = __builtin_amdgcn_mfma_f32_16x16x32_bf16(afh[i], bgh[j], a, 0, 0, 0);
        a = __builtin_amdgcn_mfma_f32_16x16x32_bf16(afh[i], bgl[j], a, 0, 0, 0);
        a = __builtin_amdgcn_mfma_f32_16x16x32_bf16(afl[i], bgh[j], a, 0, 0, 0);
        acc[i][j] = a;
      }
    __syncthreads();
  }

  // epilogue: C/D layout col=lane&15, row=quad*4+reg
  float bv[4], wv[4];
  const int slice = FUSE_NORM ? (bn >> 10) : 2;   // 0=q,1=k,2=v
  #pragma unroll
  for (int j = 0; j < 4; ++j) {
    bv[j] = bias[bn + wn + j * 16 + l16];
    if (FUSE_NORM && slice < 2)
      wv[j] = (slice ? kn : qn)[j * 16 + l16];    // d = j*16+l16
  }

  #pragma unroll
  for (int i = 0; i < 4; ++i) {
    float val[4][4];
    #pragma unroll
    for (int j = 0; j < 4; ++j)
      #pragma unroll
      for (int r = 0; r < 4; ++r)
        val[j][r] = acc[i][j][r] + bv[j];

    if (FUSE_NORM && slice < 2) {
      #pragma unroll
      for (int r = 0; r < 4; ++r) {
        float ss = val[0][r] * val[0][r];
        #pragma unroll
        for (int j = 1; j < 4; ++j) ss += val[j][r] * val[j][r];
        #pragma unroll
        for (int d = 1; d < 16; d <<= 1) ss += __shfl_xor(ss, d, 64);
        float rinv = rsqrtf(ss * (1.0f / 64.0f) + 1e-6f);
        if (slice == 0) rinv *= 0.125f;           // q * D^-0.5
        #pragma unroll
        for (int j = 0; j < 4; ++j) val[j][r] = wv[j] * (val[j][r] * rinv);
      }
    }

    #pragma unroll
    for (int j = 0; j < 4; ++j) {
      const int n = bn + wn + j * 16 + l16;
      #pragma unroll
      for (int r = 0; r < 4; ++r) {
        const int m = bm + wm + i * 16 + quad * 4 + r;
        if (OUTF32) {
          OutF[(size_t)m * Nn + n] = val[j][r];
        } else {
          unsigned short hh, ll;
          split2(val[j][r], hh, ll);
          OutH[(size_t)m * Nn + n] = hh;
          OutL[(size_t)m * Nn + n] = ll;
        }
      }
    }
  }
}

// ---- flash attention v3: K LDS double-buffered (1 barrier/iter), V direct ----
// 256 threads, 4 waves x 16 q-rows. K staged via register prefetch into padded
// (P=72) dbuf; V/mask fragments straight from VT/global (contiguous 16B).
// Static-max softmax (|S|<=8.01); per-lane l partials reduced once at end.
__global__ __launch_bounds__(256, 3)
void attn_kernel(unsigned short* __restrict__ H, unsigned short* __restrict__ L,
                 const unsigned short* __restrict__ VTH,
                 const unsigned short* __restrict__ VTL,
                 const int* __restrict__ mask)
{
  constexpr int P = 72;
  __shared__ __align__(16) unsigned short KtH[2][64 * P], KtL[2][64 * P]; // 36.9 KB
  __shared__ __align__(16) unsigned short Pt[4][16 * P];                  //  9.2 KB

  const int t    = threadIdx.x;
  const int wave = t >> 6;
  const int lane = t & 63;
  const int quad = lane >> 4;
  const int l16  = lane & 15;
  const int bh = blockIdx.y;
  const int b  = bh >> 4;
  const int h  = bh & 15;
  const int q0 = blockIdx.x * 64 + wave * 16;

  // K staging geometry: 2 chunks of 8 u16 per thread per plane
  const int row0 = t >> 3,         col0 = (t & 7) * 8;
  const int row1 = (256 + t) >> 3, col1 = ((256 + t) & 7) * 8;

  // Q fragments (A-layout: m=l16, k=quad*8+j)
  bhalf8 qfh[2], qfl[2];
  {
    const size_t qrow = (size_t)(b * kN + q0 + l16) * k3C + h * kD;
    qfh[0] = *(const bhalf8*)(&H[qrow + quad * 8]);
    qfh[1] = *(const bhalf8*)(&H[qrow + 32 + quad * 8]);
    qfl[0] = *(const bhalf8*)(&L[qrow + quad * 8]);
    qfl[1] = *(const bhalf8*)(&L[qrow + 32 + quad * 8]);
  }

  f32x4 acc_o[4] = {};
  float lpart[4] = {};

  uint4 skh0, skh1, skl0, skl1;        // K staging regs
  bhalf8 vfh[4][2], vfl[4][2];         // V fragments (current tile)
  int mcur[4], mnext[4];

  auto prefK = [&](int kt) {
    const size_t g0 = (size_t)(b * kN + kt + row0) * k3C + kC + h * kD + col0;
    const size_t g1 = (size_t)(b * kN + kt + row1) * k3C + kC + h * kD + col1;
    skh0 = *(const uint4*)(&H[g0]); skh1 = *(const uint4*)(&H[g1]);
    skl0 = *(const uint4*)(&L[g0]); skl1 = *(const uint4*)(&L[g1]);
  };
  auto storeK = [&](int buf) {
    *(uint4*)(&KtH[buf][row0 * P + col0]) = skh0;
    *(uint4*)(&KtH[buf][row1 * P + col1]) = skh1;
    *(uint4*)(&KtL[buf][row0 * P + col0]) = skl0;
    *(uint4*)(&KtL[buf][row1 * P + col1]) = skl1;
  };
  auto loadM = [&](int kt, int* m) {
    #pragma unroll
    for (int nt = 0; nt < 4; ++nt) m[nt] = mask[b * kN + kt + nt * 16 + l16];
  };

  prefK(0);
  loadM(0, mcur);
  storeK(0);
  __syncthreads();

  for (int i = 0; i < 32; ++i) {
    const int kt = i * 64;
    const int cb = i & 1;

    // current tile's V fragments (used ~QK-phase later; L2 latency hidden)
    #pragma unroll
    for (int dt = 0; dt < 4; ++dt) {
      const size_t vg = ((size_t)bh * kD + dt * 16 + l16) * kN + kt + quad * 8;
      vfh[dt][0] = *(const bhalf8*)(&VTH[vg]);
      vfh[dt][1] = *(const bhalf8*)(&VTH[vg + 32]);
      vfl[dt][0] = *(const bhalf8*)(&VTL[vg]);
      vfl[dt][1] = *(const bhalf8*)(&VTL[vg + 32]);
    }
    if (i < 31) { prefK(kt + 64); loadM(kt + 64, mnext); }

    // S = QhKh + QhKl + QlKh ; p = flag*exp(s) -> Pt (C-layout -> A-layout)
    #pragma unroll
    for (int nt = 0; nt < 4; ++nt) {
      const int kr = (nt * 16 + l16) * P + quad * 8;
      const bhalf8 kh0 = *(const bhalf8*)(&KtH[cb][kr]);
      const bhalf8 kh1 = *(const bhalf8*)(&KtH[cb][kr + 32]);
      const bhalf8 kl0 = *(const bhalf8*)(&KtL[cb][kr]);
      const bhalf8 kl1 = *(const bhalf8*)(&KtL[cb][kr + 32]);
      const float flag = mcur[nt] ? 1.0f : 0.0f;
      f32x4 s = {};
      s = __builtin_amdgcn_mfma_f32_16x16x32_bf16(qfh[0], kh0, s, 0, 0, 0);
      s = __builtin_amdgcn_mfma_f32_16x16x32_bf16(qfh[1], kh1, s, 0, 0, 0);
      s = __builtin_amdgcn_mfma_f32_16x16x32_bf16(qfh[0], kl0, s, 0, 0, 0);
      s = __builtin_amdgcn_mfma_f32_16x16x32_bf16(qfh[1], kl1, s, 0, 0, 0);
      s = __builtin_amdgcn_mfma_f32_16x16x32_bf16(qfl[0], kh0, s, 0, 0, 0);
      s = __builtin_amdgcn_mfma_f32_16x16x32_bf16(qfl[1], kh1, s, 0, 0, 0);
      #pragma unroll
      for (int r = 0; r < 4; ++r) {
        const float p = flag * __expf(s[r]);    // s in [-8.01, 8.01]
        lpart[r] += p;
        Pt[wave][(quad * 4 + r) * P + nt * 16 + l16] = f2bf(p);
      }
    }

    // O += P (Vh + Vl)   (Pt per-wave: same-wave DS ordering, no barrier)
    #pragma unroll
    for (int kk = 0; kk < 2; ++kk) {
      const bhalf8 pa = *(const bhalf8*)(&Pt[wave][l16 * P + kk * 32 + quad * 8]);
      #pragma unroll
      for (int dt = 0; dt < 4; ++dt) {
        acc_o[dt] = __builtin_amdgcn_mfma_f32_16x16x32_bf16(pa, vfh[dt][kk], acc_o[dt], 0, 0, 0);
        acc_o[dt] = __builtin_amdgcn_mfma_f32_16x16x32_bf16(pa, vfl[dt][kk], acc_o[dt], 0, 0, 0);
      }
    }

    if (i < 31) {
      storeK(1 - cb);    // buf[1-cb]'s last readers finished before prev barrier
      #pragma unroll
      for (int nt = 0; nt < 4; ++nt) mcur[nt] = mnext[nt];
    }
    __syncthreads();     // publishes staged K for next iter (drains vm+lgkm)
  }

  // final l reduction + normalize + store hi/lo into q-slice
  #pragma unroll
  for (int r = 0; r < 4; ++r) {
    float s = lpart[r];
    #pragma unroll
    for (int d = 1; d < 16; d <<= 1) s += __shfl_xor(s, d, 64);
    lpart[r] = s;
  }
  #pragma unroll
  for (int dt = 0; dt < 4; ++dt)
    #pragma unroll
    for (int r = 0; r < 4; ++r) {
      const int qrow = q0 + quad * 4 + r;
      const float inv = 1.0f / fmaxf(lpart[r], 1.0e-30f);
      const size_t off = (size_t)(b * kN + qrow) * k3C + h * kD + dt * 16 + l16;
      unsigned short hh, ll;
      split2(acc_o[dt][r] * inv, hh, ll);
      H[off] = hh; L[off] = ll;
    }
}

} // anonymous namespace

extern "C" void kernel_launch(void* const* d_in, const int* in_sizes, int n_in,
                              void* d_out, int out_size, void* d_ws, size_t ws_size,
                              hipStream_t stream)
{
  const float* x      = (const float*)d_in[0];
  const int*   maskp  = (const int*)d_in[1];
  const float* qkv_w  = (const float*)d_in[2];
  const float* qkv_b  = (const float*)d_in[3];
  const float* proj_w = (const float*)d_in[4];
  const float* proj_b = (const float*)d_in[5];
  const float* qn_w   = (const float*)d_in[6];
  const float* kn_w   = (const float*)d_in[7];
  float* out = (float*)d_out;

  unsigned short* qH = (unsigned short*)d_ws;      // qkv hi plane
  unsigned short* qL = qH + kPS;                   // qkv lo plane
  unsigned short* R1 = qL + kPS;                   // x planes -> later VT planes
  unsigned short* R2 = R1 + 2 * kXE;               // qkv_w planes -> later proj_w planes
  unsigned short* xH = R1,  *xL = R1 + kXE;
  unsigned short* VTH = R1, *VTL = R1 + kXE;
  unsigned short* wqH = R2, *wqL = R2 + kWQ;
  unsigned short* wpH = R2, *wpL = R2 + kWP;

  split_planes<<<(int)(kXE / 4 / 256), 256, 0, stream>>>(x, xH, xL, (int)(kXE / 4));
  split_planes<<<(int)(kWQ / 4 / 256), 256, 0, stream>>>(qkv_w, wqH, wqL, (int)(kWQ / 4));

  // 1) qkv = x @ qkv_w^T + qkv_b, RMSNorm(q,k) fused into epilogue
  gemm_planes<false, true><<<dim3(kTok / 128, k3C / 128), 256, 0, stream>>>(
      xH, xL, kC, wqH, wqL, qkv_b, nullptr, qH, qL, qn_w, kn_w, k3C, kC);

  // 2) pre-transpose V (overwrites x planes) ; pre-split proj_w (overwrites qkv_w)
  vt_transpose<<<2048, 256, 0, stream>>>(qH, qL, VTH, VTL);
  split_planes<<<(int)(kWP / 4 / 256), 256, 0, stream>>>(proj_w, wpH, wpL, (int)(kWP / 4));

  // 3) masked flash attention; result into q-slice of planes
  attn_kernel<<<dim3(kN / 64, kB * kH), 256, 0, stream>>>(qH, qL, VTH, VTL, maskp);

  // 4) out = attn @ proj_w^T + proj_b
  gemm_planes<true, false><<<dim3(kTok / 128, kC / 128), 256, 0, stream>>>(
      qH, qL, k3C, wpH, wpL, proj_b, out, nullptr, nullptr, nullptr, nullptr, kC, kC);
}

// Round 9
// 472.143 us; speedup vs baseline: 1.0675x; 1.0675x over previous
//
#include <hip/hip_runtime.h>
#include <hip/hip_bf16.h>
#include <stdint.h>

namespace {

constexpr int kB = 2;
constexpr int kN = 2048;
constexpr int kC = 1024;
constexpr int kH = 16;
constexpr int kD = 64;
constexpr int kTok = kB * kN;               // 4096
constexpr int k3C  = 3 * kC;                // 3072
constexpr size_t kPS = (size_t)kTok * k3C;  // qkv plane elems
constexpr size_t kXE = (size_t)kTok * kC;   // x / VT plane elems
constexpr size_t kWQ = (size_t)k3C * kC;    // qkv_w elems
constexpr size_t kWP = (size_t)kC * kC;     // proj_w elems

using bhalf8 = __attribute__((ext_vector_type(8))) __bf16;
using f32x4  = __attribute__((ext_vector_type(4))) float;

__device__ inline unsigned short f2bf(float f) {
  __hip_bfloat16 h = __float2bfloat16(f);
  return *reinterpret_cast<unsigned short*>(&h);
}
__device__ inline float bf2f(unsigned short u) {
  __hip_bfloat16 h;
  *reinterpret_cast<unsigned short*>(&h) = u;
  return __bfloat162float(h);
}
__device__ inline void split2(float v, unsigned short& h, unsigned short& l) {
  const unsigned short hb = f2bf(v);
  h = hb;
  l = f2bf(v - bf2f(hb));
}

// async global->LDS, 16B per lane; LDS dest must be wave-uniform base + lane*16
__device__ inline void glds16(const unsigned short* g, unsigned short* l) {
  __builtin_amdgcn_global_load_lds(
      (const __attribute__((address_space(1))) void*)g,
      (__attribute__((address_space(3))) void*)l, 16, 0, 0);
}

// ---- split fp32 -> bf16 hi/lo planes ----
__global__ __launch_bounds__(256)
void split_planes(const float* __restrict__ src,
                  unsigned short* __restrict__ H,
                  unsigned short* __restrict__ L, int n4)
{
  const int i = blockIdx.x * 256 + threadIdx.x;
  if (i >= n4) return;
  const float4 v = ((const float4*)src)[i];
  ushort4 hh, ll;
  split2(v.x, hh.x, ll.x); split2(v.y, hh.y, ll.y);
  split2(v.z, hh.z, ll.z); split2(v.w, hh.w, ll.w);
  ((ushort4*)H)[i] = hh;
  ((ushort4*)L)[i] = ll;
}

// ---- pre-transpose V (hi plane only) into VT[bh][d][token] ----
__global__ __launch_bounds__(256)
void vt_transpose(const unsigned short* __restrict__ H,
                  unsigned short* __restrict__ VTH)
{
  const int gw   = blockIdx.x * 4 + (threadIdx.x >> 6);  // 0..8191
  const int lane = threadIdx.x & 63;                     // = d
  const int bh   = gw >> 8;
  const int oct  = gw & 255;
  const int b = bh >> 4, h = bh & 15;
  const int tok0 = oct * 8;
  union { unsigned short u[8]; uint4 v; } ph;
  #pragma unroll
  for (int e = 0; e < 8; ++e) {
    const size_t g = (size_t)(b * kN + tok0 + e) * k3C + 2 * kC + h * kD + lane;
    ph.u[e] = H[g];
  }
  *(uint4*)(&VTH[((size_t)bh * kD + lane) * kN + tok0]) = ph.v;
}

// ---- plane GEMM: C = (AH+AL) @ (WH+WL)^T + bias; 3-term MFMA; m97 staging ----
// FUSE_NORM: RMSNorm q,k in epilogue; lo-plane written only for q slice
// (k,v lo-planes are never read downstream: attn uses K,V hi only).
template<bool OUTF32, bool FUSE_NORM>
__global__ __launch_bounds__(256)
void gemm_planes(const unsigned short* __restrict__ AH,
                 const unsigned short* __restrict__ AL, int lda,
                 const unsigned short* __restrict__ WH,
                 const unsigned short* __restrict__ WL,
                 const float* __restrict__ bias,
                 float* __restrict__ OutF,
                 unsigned short* __restrict__ OutH,
                 unsigned short* __restrict__ OutL,
                 const float* __restrict__ qn,
                 const float* __restrict__ kn,
                 int Nn, int K)
{
  __shared__ __align__(16) unsigned short AsH[128 * 32], AsL[128 * 32];
  __shared__ __align__(16) unsigned short BsH[128 * 32], BsL[128 * 32];

  const int t    = threadIdx.x;
  const int wave = t >> 6;
  const int lane = t & 63;
  const int quad = lane >> 4;
  const int l16  = lane & 15;
  const int bm = blockIdx.x * 128;
  const int bn = blockIdx.y * 128;
  const int wm = (wave >> 1) * 64;
  const int wn = (wave & 1) * 64;

  f32x4 acc[4][4] = {};

  for (int k0 = 0; k0 < K; k0 += 32) {
    #pragma unroll
    for (int r = 0; r < 2; ++r) {
      const int c   = r * 256 + t;
      const int row = c >> 2;
      const int col = (c & 3) * 8;
      glds16(&AH[(size_t)(bm + row) * lda + k0 + col], &AsH[c * 8]);
      glds16(&AL[(size_t)(bm + row) * lda + k0 + col], &AsL[c * 8]);
      glds16(&WH[(size_t)(bn + row) * K + k0 + col], &BsH[c * 8]);
      glds16(&WL[(size_t)(bn + row) * K + k0 + col], &BsL[c * 8]);
    }
    __syncthreads();

    bhalf8 afh[4], afl[4], bgh[4], bgl[4];
    #pragma unroll
    for (int i = 0; i < 4; ++i) {
      afh[i] = *(const bhalf8*)(&AsH[(wm + i * 16 + l16) * 32 + quad * 8]);
      afl[i] = *(const bhalf8*)(&AsL[(wm + i * 16 + l16) * 32 + quad * 8]);
      bgh[i] = *(const bhalf8*)(&BsH[(wn + i * 16 + l16) * 32 + quad * 8]);
      bgl[i] = *(const bhalf8*)(&BsL[(wn + i * 16 + l16) * 32 + quad * 8]);
    }
    #pragma unroll
    for (int i = 0; i < 4; ++i)
      #pragma unroll
      for (int j = 0; j < 4; ++j) {
        f32x4 a = acc[i][j];
        a = __builtin_amdgcn_mfma_f32_16x16x32_bf16(afh[i], bgh[j], a, 0, 0, 0);
        a = __builtin_amdgcn_mfma_f32_16x16x32_bf16(afh[i], bgl[j], a, 0, 0, 0);
        a = __builtin_amdgcn_mfma_f32_16x16x32_bf16(afl[i], bgh[j], a, 0, 0, 0);
        acc[i][j] = a;
      }
    __syncthreads();
  }

  // epilogue: C/D layout col=lane&15, row=quad*4+reg
  float bv[4], wv[4];
  const int slice = FUSE_NORM ? (bn >> 10) : 0;   // 0=q,1=k,2=v
  const bool writeL = !FUSE_NORM || slice == 0;
  #pragma unroll
  for (int j = 0; j < 4; ++j) {
    bv[j] = bias[bn + wn + j * 16 + l16];
    if (FUSE_NORM && slice < 2)
      wv[j] = (slice ? kn : qn)[j * 16 + l16];    // d = j*16+l16
  }

  #pragma unroll
  for (int i = 0; i < 4; ++i) {
    float val[4][4];
    #pragma unroll
    for (int j = 0; j < 4; ++j)
      #pragma unroll
      for (int r = 0; r < 4; ++r)
        val[j][r] = acc[i][j][r] + bv[j];

    if (FUSE_NORM && slice < 2) {
      #pragma unroll
      for (int r = 0; r < 4; ++r) {
        float ss = val[0][r] * val[0][r];
        #pragma unroll
        for (int j = 1; j < 4; ++j) ss += val[j][r] * val[j][r];
        #pragma unroll
        for (int d = 1; d < 16; d <<= 1) ss += __shfl_xor(ss, d, 64);
        float rinv = rsqrtf(ss * (1.0f / 64.0f) + 1e-6f);
        if (slice == 0) rinv *= 0.125f;           // q * D^-0.5
        #pragma unroll
        for (int j = 0; j < 4; ++j) val[j][r] = wv[j] * (val[j][r] * rinv);
      }
    }

    #pragma unroll
    for (int j = 0; j < 4; ++j) {
      const int n = bn + wn + j * 16 + l16;
      #pragma unroll
      for (int r = 0; r < 4; ++r) {
        const int m = bm + wm + i * 16 + quad * 4 + r;
        if (OUTF32) {
          OutF[(size_t)m * Nn + n] = val[j][r];
        } else {
          unsigned short hh, ll;
          split2(val[j][r], hh, ll);
          OutH[(size_t)m * Nn + n] = hh;
          if (writeL) OutL[(size_t)m * Nn + n] = ll;
        }
      }
    }
  }
}

// ---- flash attention v4: r6 structure, single-precision K/V ----
// 256 threads, 4 waves x 32 q-rows (2 groups of 16). K,V (hi plane only)
// staged via register prefetch into padded LDS (P=72); Q stays 2-term.
// S = (Qh+Ql)Kh (2 MFMA/chunk-pair/nt), O += P*Vh (1 term). Static-max
// softmax (|S|<=8.02); per-lane l partials reduced once at end.
__global__ __launch_bounds__(256, 4)
void attn_kernel(unsigned short* __restrict__ H, unsigned short* __restrict__ L,
                 const unsigned short* __restrict__ VTH,
                 const int* __restrict__ mask)
{
  constexpr int P = 72;
  __shared__ __align__(16) unsigned short KtH[64 * P];   //  9.2 KB [key][d]
  __shared__ __align__(16) unsigned short VtH[64 * P];   //  9.2 KB [d][key]
  __shared__ __align__(16) unsigned short Pt[4][32 * P]; // 18.4 KB per-wave [q][key]

  const int t    = threadIdx.x;
  const int wave = t >> 6;
  const int lane = t & 63;
  const int quad = lane >> 4;
  const int l16  = lane & 15;
  const int bh = blockIdx.y;
  const int b  = bh >> 4;
  const int h  = bh & 15;
  const int q0 = blockIdx.x * 128 + wave * 32;  // 32 q-rows/wave

  // staging geometry: 2 chunks of 8 u16 per thread per tile
  const int row0 = t >> 3,         col0 = (t & 7) * 8;
  const int row1 = (256 + t) >> 3, col1 = ((256 + t) & 7) * 8;

  // Q fragments, both groups (A-layout: m=l16, k=quad*8+j)
  bhalf8 qfh[2][2], qfl[2][2];
  #pragma unroll
  for (int g = 0; g < 2; ++g) {
    const size_t qrow = (size_t)(b * kN + q0 + g * 16 + l16) * k3C + h * kD;
    qfh[g][0] = *(const bhalf8*)(&H[qrow + quad * 8]);
    qfh[g][1] = *(const bhalf8*)(&H[qrow + 32 + quad * 8]);
    qfl[g][0] = *(const bhalf8*)(&L[qrow + quad * 8]);
    qfl[g][1] = *(const bhalf8*)(&L[qrow + 32 + quad * 8]);
  }

  f32x4 acc_o[2][4] = {};
  float lpart[2][4] = {};

  uint4 sk0, sk1, sv0, sv1;            // staging regs
  int mcur[4], mnext[4];

  auto pref = [&](int kt) {
    sk0 = *(const uint4*)(&H[(size_t)(b * kN + kt + row0) * k3C + kC + h * kD + col0]);
    sk1 = *(const uint4*)(&H[(size_t)(b * kN + kt + row1) * k3C + kC + h * kD + col1]);
    sv0 = *(const uint4*)(&VTH[((size_t)bh * kD + row0) * kN + kt + col0]);
    sv1 = *(const uint4*)(&VTH[((size_t)bh * kD + row1) * kN + kt + col1]);
  };
  auto loadM = [&](int kt, int* m) {
    #pragma unroll
    for (int nt = 0; nt < 4; ++nt) m[nt] = mask[b * kN + kt + nt * 16 + l16];
  };

  pref(0);
  loadM(0, mcur);

  for (int i = 0; i < 32; ++i) {
    const int kt = i * 64;
    // drain staged regs into LDS
    *(uint4*)(&KtH[row0 * P + col0]) = sk0;
    *(uint4*)(&KtH[row1 * P + col1]) = sk1;
    *(uint4*)(&VtH[row0 * P + col0]) = sv0;
    *(uint4*)(&VtH[row1 * P + col1]) = sv1;
    __syncthreads();

    // issue next tile's global loads early; consumed next iter
    if (i < 31) { pref(kt + 64); loadM(kt + 64, mnext); }

    // S = (Qh+Ql)Kh ; p = flag*exp(s) -> Pt (C-layout -> A-layout)
    #pragma unroll
    for (int nt = 0; nt < 4; ++nt) {
      const int kr = (nt * 16 + l16) * P + quad * 8;
      const bhalf8 kh0 = *(const bhalf8*)(&KtH[kr]);
      const bhalf8 kh1 = *(const bhalf8*)(&KtH[kr + 32]);
      const float flag = mcur[nt] ? 1.0f : 0.0f;
      #pragma unroll
      for (int g = 0; g < 2; ++g) {
        f32x4 s = {};
        s = __builtin_amdgcn_mfma_f32_16x16x32_bf16(qfh[g][0], kh0, s, 0, 0, 0);
        s = __builtin_amdgcn_mfma_f32_16x16x32_bf16(qfh[g][1], kh1, s, 0, 0, 0);
        s = __builtin_amdgcn_mfma_f32_16x16x32_bf16(qfl[g][0], kh0, s, 0, 0, 0);
        s = __builtin_amdgcn_mfma_f32_16x16x32_bf16(qfl[g][1], kh1, s, 0, 0, 0);
        #pragma unroll
        for (int r = 0; r < 4; ++r) {
          const float p = flag * __expf(s[r]);   // s in [-8.02, 8.02]
          lpart[g][r] += p;
          Pt[wave][(g * 16 + quad * 4 + r) * P + nt * 16 + l16] = f2bf(p);
        }
      }
    }

    // O += P * Vh  (Pt per-wave: same-wave DS ordering, no barrier needed)
    #pragma unroll
    for (int kk = 0; kk < 2; ++kk) {
      const bhalf8 pa0 = *(const bhalf8*)(&Pt[wave][l16 * P + kk * 32 + quad * 8]);
      const bhalf8 pa1 = *(const bhalf8*)(&Pt[wave][(16 + l16) * P + kk * 32 + quad * 8]);
      #pragma unroll
      for (int dt = 0; dt < 4; ++dt) {
        const bhalf8 vb = *(const bhalf8*)(&VtH[(dt * 16 + l16) * P + kk * 32 + quad * 8]);
        acc_o[0][dt] = __builtin_amdgcn_mfma_f32_16x16x32_bf16(pa0, vb, acc_o[0][dt], 0, 0, 0);
        acc_o[1][dt] = __builtin_amdgcn_mfma_f32_16x16x32_bf16(pa1, vb, acc_o[1][dt], 0, 0, 0);
      }
    }

    #pragma unroll
    for (int nt = 0; nt < 4; ++nt) mcur[nt] = mnext[nt];
    __syncthreads();     // Kt/Vt readers done; next iter may overwrite
  }

  // final l reduction + normalize + store hi/lo into q-slice
  #pragma unroll
  for (int g = 0; g < 2; ++g)
    #pragma unroll
    for (int r = 0; r < 4; ++r) {
      float s = lpart[g][r];
      #pragma unroll
      for (int d = 1; d < 16; d <<= 1) s += __shfl_xor(s, d, 64);
      lpart[g][r] = s;
    }
  #pragma unroll
  for (int g = 0; g < 2; ++g)
    #pragma unroll
    for (int dt = 0; dt < 4; ++dt)
      #pragma unroll
      for (int r = 0; r < 4; ++r) {
        const int qrow = q0 + g * 16 + quad * 4 + r;
        const float inv = 1.0f / fmaxf(lpart[g][r], 1.0e-30f);
        const size_t off = (size_t)(b * kN + qrow) * k3C + h * kD + dt * 16 + l16;
        unsigned short hh, ll;
        split2(acc_o[g][dt][r] * inv, hh, ll);
        H[off] = hh; L[off] = ll;
      }
}

} // anonymous namespace

extern "C" void kernel_launch(void* const* d_in, const int* in_sizes, int n_in,
                              void* d_out, int out_size, void* d_ws, size_t ws_size,
                              hipStream_t stream)
{
  const float* x      = (const float*)d_in[0];
  const int*   maskp  = (const int*)d_in[1];
  const float* qkv_w  = (const float*)d_in[2];
  const float* qkv_b  = (const float*)d_in[3];
  const float* proj_w = (const float*)d_in[4];
  const float* proj_b = (const float*)d_in[5];
  const float* qn_w   = (const float*)d_in[6];
  const float* kn_w   = (const float*)d_in[7];
  float* out = (float*)d_out;

  unsigned short* qH = (unsigned short*)d_ws;      // qkv hi plane
  unsigned short* qL = qH + kPS;                   // qkv lo plane
  unsigned short* R1 = qL + kPS;                   // x planes -> later VT plane
  unsigned short* R2 = R1 + 2 * kXE;               // qkv_w planes -> later proj_w planes
  unsigned short* xH = R1,  *xL = R1 + kXE;
  unsigned short* VTH = R1;                        // reuse after gemm1
  unsigned short* wqH = R2, *wqL = R2 + kWQ;
  unsigned short* wpH = R2, *wpL = R2 + kWP;

  split_planes<<<(int)(kXE / 4 / 256), 256, 0, stream>>>(x, xH, xL, (int)(kXE / 4));
  split_planes<<<(int)(kWQ / 4 / 256), 256, 0, stream>>>(qkv_w, wqH, wqL, (int)(kWQ / 4));

  // 1) qkv = x @ qkv_w^T + qkv_b, RMSNorm(q,k) fused; lo written for q only
  gemm_planes<false, true><<<dim3(kTok / 128, k3C / 128), 256, 0, stream>>>(
      xH, xL, kC, wqH, wqL, qkv_b, nullptr, qH, qL, qn_w, kn_w, k3C, kC);

  // 2) pre-transpose V hi (overwrites x planes); pre-split proj_w
  vt_transpose<<<2048, 256, 0, stream>>>(qH, VTH);
  split_planes<<<(int)(kWP / 4 / 256), 256, 0, stream>>>(proj_w, wpH, wpL, (int)(kWP / 4));

  // 3) masked flash attention; result into q-slice of planes
  attn_kernel<<<dim3(kN / 128, kB * kH), 256, 0, stream>>>(qH, qL, VTH, maskp);

  // 4) out = attn @ proj_w^T + proj_b
  gemm_planes<true, false><<<dim3(kTok / 128, kC / 128), 256, 0, stream>>>(
      qH, qL, k3C, wpH, wpL, proj_b, out, nullptr, nullptr, nullptr, nullptr, kC, kC);
}

// Round 10
// 441.484 us; speedup vs baseline: 1.1416x; 1.0694x over previous
//
#include <hip/hip_runtime.h>
#include <hip/hip_bf16.h>
#include <stdint.h>

namespace {

constexpr int kB = 2;
constexpr int kN = 2048;
constexpr int kC = 1024;
constexpr int kH = 16;
constexpr int kD = 64;
constexpr int kTok = kB * kN;               // 4096
constexpr int k3C  = 3 * kC;                // 3072
constexpr size_t kPS = (size_t)kTok * k3C;  // qkv plane elems
constexpr size_t kXE = (size_t)kTok * kC;   // x / VT plane elems
constexpr size_t kWQ = (size_t)k3C * kC;    // qkv_w elems
constexpr size_t kWP = (size_t)kC * kC;     // proj_w elems

using bhalf8 = __attribute__((ext_vector_type(8))) __bf16;
using f32x4  = __attribute__((ext_vector_type(4))) float;

__device__ inline unsigned short f2bf(float f) {
  __hip_bfloat16 h = __float2bfloat16(f);
  return *reinterpret_cast<unsigned short*>(&h);
}
__device__ inline float bf2f(unsigned short u) {
  __hip_bfloat16 h;
  *reinterpret_cast<unsigned short*>(&h) = u;
  return __bfloat162float(h);
}
__device__ inline void split2(float v, unsigned short& h, unsigned short& l) {
  const unsigned short hb = f2bf(v);
  h = hb;
  l = f2bf(v - bf2f(hb));
}

// async global->LDS, 16B per lane; LDS dest must be wave-uniform base + lane*16
__device__ inline void glds16(const unsigned short* g, unsigned short* l) {
  __builtin_amdgcn_global_load_lds(
      (const __attribute__((address_space(1))) void*)g,
      (__attribute__((address_space(3))) void*)l, 16, 0, 0);
}

// ---- split fp32 -> bf16 hi/lo planes ----
__global__ __launch_bounds__(256)
void split_planes(const float* __restrict__ src,
                  unsigned short* __restrict__ H,
                  unsigned short* __restrict__ L, int n4)
{
  const int i = blockIdx.x * 256 + threadIdx.x;
  if (i >= n4) return;
  const float4 v = ((const float4*)src)[i];
  ushort4 hh, ll;
  split2(v.x, hh.x, ll.x); split2(v.y, hh.y, ll.y);
  split2(v.z, hh.z, ll.z); split2(v.w, hh.w, ll.w);
  ((ushort4*)H)[i] = hh;
  ((ushort4*)L)[i] = ll;
}

// ---- pre-transpose V (hi plane only) into VT[bh][d][token] ----
__global__ __launch_bounds__(256)
void vt_transpose(const unsigned short* __restrict__ H,
                  unsigned short* __restrict__ VTH)
{
  const int gw   = blockIdx.x * 4 + (threadIdx.x >> 6);  // 0..8191
  const int lane = threadIdx.x & 63;                     // = d
  const int bh   = gw >> 8;
  const int oct  = gw & 255;
  const int b = bh >> 4, h = bh & 15;
  const int tok0 = oct * 8;
  union { unsigned short u[8]; uint4 v; } ph;
  #pragma unroll
  for (int e = 0; e < 8; ++e) {
    const size_t g = (size_t)(b * kN + tok0 + e) * k3C + 2 * kC + h * kD + lane;
    ph.u[e] = H[g];
  }
  *(uint4*)(&VTH[((size_t)bh * kD + lane) * kN + tok0]) = ph.v;
}

// ---- plane GEMM: C = (AH+AL) @ (WH+WL)^T + bias; 3-term MFMA; m97 staging ----
template<bool OUTF32, bool FUSE_NORM>
__global__ __launch_bounds__(256)
void gemm_planes(const unsigned short* __restrict__ AH,
                 const unsigned short* __restrict__ AL, int lda,
                 const unsigned short* __restrict__ WH,
                 const unsigned short* __restrict__ WL,
                 const float* __restrict__ bias,
                 float* __restrict__ OutF,
                 unsigned short* __restrict__ OutH,
                 unsigned short* __restrict__ OutL,
                 const float* __restrict__ qn,
                 const float* __restrict__ kn,
                 int Nn, int K)
{
  __shared__ __align__(16) unsigned short AsH[128 * 32], AsL[128 * 32];
  __shared__ __align__(16) unsigned short BsH[128 * 32], BsL[128 * 32];

  const int t    = threadIdx.x;
  const int wave = t >> 6;
  const int lane = t & 63;
  const int quad = lane >> 4;
  const int l16  = lane & 15;
  const int bm = blockIdx.x * 128;
  const int bn = blockIdx.y * 128;
  const int wm = (wave >> 1) * 64;
  const int wn = (wave & 1) * 64;

  f32x4 acc[4][4] = {};

  for (int k0 = 0; k0 < K; k0 += 32) {
    #pragma unroll
    for (int r = 0; r < 2; ++r) {
      const int c   = r * 256 + t;
      const int row = c >> 2;
      const int col = (c & 3) * 8;
      glds16(&AH[(size_t)(bm + row) * lda + k0 + col], &AsH[c * 8]);
      glds16(&AL[(size_t)(bm + row) * lda + k0 + col], &AsL[c * 8]);
      glds16(&WH[(size_t)(bn + row) * K + k0 + col], &BsH[c * 8]);
      glds16(&WL[(size_t)(bn + row) * K + k0 + col], &BsL[c * 8]);
    }
    __syncthreads();

    bhalf8 afh[4], afl[4], bgh[4], bgl[4];
    #pragma unroll
    for (int i = 0; i < 4; ++i) {
      afh[i] = *(const bhalf8*)(&AsH[(wm + i * 16 + l16) * 32 + quad * 8]);
      afl[i] = *(const bhalf8*)(&AsL[(wm + i * 16 + l16) * 32 + quad * 8]);
      bgh[i] = *(const bhalf8*)(&BsH[(wn + i * 16 + l16) * 32 + quad * 8]);
      bgl[i] = *(const bhalf8*)(&BsL[(wn + i * 16 + l16) * 32 + quad * 8]);
    }
    #pragma unroll
    for (int i = 0; i < 4; ++i)
      #pragma unroll
      for (int j = 0; j < 4; ++j) {
        f32x4 a = acc[i][j];
        a = __builtin_amdgcn_mfma_f32_16x16x32_bf16(afh[i], bgh[j], a, 0, 0, 0);
        a = __builtin_amdgcn_mfma_f32_16x16x32_bf16(afh[i], bgl[j], a, 0, 0, 0);
        a = __builtin_amdgcn_mfma_f32_16x16x32_bf16(afl[i], bgh[j], a, 0, 0, 0);
        acc[i][j] = a;
      }
    __syncthreads();
  }

  // epilogue: C/D layout col=lane&15, row=quad*4+reg
  float bv[4], wv[4];
  const int slice = FUSE_NORM ? (bn >> 10) : 0;   // 0=q,1=k,2=v
  const bool writeL = !FUSE_NORM || slice == 0;
  #pragma unroll
  for (int j = 0; j < 4; ++j) {
    bv[j] = bias[bn + wn + j * 16 + l16];
    if (FUSE_NORM && slice < 2)
      wv[j] = (slice ? kn : qn)[j * 16 + l16];    // d = j*16+l16
  }

  #pragma unroll
  for (int i = 0; i < 4; ++i) {
    float val[4][4];
    #pragma unroll
    for (int j = 0; j < 4; ++j)
      #pragma unroll
      for (int r = 0; r < 4; ++r)
        val[j][r] = acc[i][j][r] + bv[j];

    if (FUSE_NORM && slice < 2) {
      #pragma unroll
      for (int r = 0; r < 4; ++r) {
        float ss = val[0][r] * val[0][r];
        #pragma unroll
        for (int j = 1; j < 4; ++j) ss += val[j][r] * val[j][r];
        #pragma unroll
        for (int d = 1; d < 16; d <<= 1) ss += __shfl_xor(ss, d, 64);
        float rinv = rsqrtf(ss * (1.0f / 64.0f) + 1e-6f);
        if (slice == 0) rinv *= 0.125f;           // q * D^-0.5
        #pragma unroll
        for (int j = 0; j < 4; ++j) val[j][r] = wv[j] * (val[j][r] * rinv);
      }
    }

    #pragma unroll
    for (int j = 0; j < 4; ++j) {
      const int n = bn + wn + j * 16 + l16;
      #pragma unroll
      for (int r = 0; r < 4; ++r) {
        const int m = bm + wm + i * 16 + quad * 4 + r;
        if (OUTF32) {
          OutF[(size_t)m * Nn + n] = val[j][r];
        } else {
          unsigned short hh, ll;
          split2(val[j][r], hh, ll);
          OutH[(size_t)m * Nn + n] = hh;
          if (writeL) OutL[(size_t)m * Nn + n] = ll;
        }
      }
    }
  }
}

// ---- flash attention v5: r9 kernel + XCD-aware block swizzle ----
// All 16 q-blocks of one (b,h) land on the same XCD (id%8 heuristic) so the
// bh's K/V (512 KB) stays L2-resident: 4 bh/XCD = 2 MB < 4 MB L2.
__global__ __launch_bounds__(256, 4)
void attn_kernel(unsigned short* __restrict__ H, unsigned short* __restrict__ L,
                 const unsigned short* __restrict__ VTH,
                 const int* __restrict__ mask)
{
  constexpr int P = 72;
  __shared__ __align__(16) unsigned short KtH[64 * P];   //  9.2 KB [key][d]
  __shared__ __align__(16) unsigned short VtH[64 * P];   //  9.2 KB [d][key]
  __shared__ __align__(16) unsigned short Pt[4][32 * P]; // 18.4 KB per-wave [q][key]

  const int t    = threadIdx.x;
  const int wave = t >> 6;
  const int lane = t & 63;
  const int quad = lane >> 4;
  const int l16  = lane & 15;

  // XCD swizzle: lin%8 = XCD (dispatch round-robin); 4 bh per XCD.
  const int lin  = blockIdx.x;          // 0..511
  const int xcd  = lin & 7;
  const int slot = lin >> 3;            // 0..63
  const int bh   = xcd + 8 * (slot >> 4);
  const int qblk = slot & 15;
  const int b  = bh >> 4;
  const int h  = bh & 15;
  const int q0 = qblk * 128 + wave * 32;  // 32 q-rows/wave

  // staging geometry: 2 chunks of 8 u16 per thread per tile
  const int row0 = t >> 3,         col0 = (t & 7) * 8;
  const int row1 = (256 + t) >> 3, col1 = ((256 + t) & 7) * 8;

  // Q fragments, both groups (A-layout: m=l16, k=quad*8+j)
  bhalf8 qfh[2][2], qfl[2][2];
  #pragma unroll
  for (int g = 0; g < 2; ++g) {
    const size_t qrow = (size_t)(b * kN + q0 + g * 16 + l16) * k3C + h * kD;
    qfh[g][0] = *(const bhalf8*)(&H[qrow + quad * 8]);
    qfh[g][1] = *(const bhalf8*)(&H[qrow + 32 + quad * 8]);
    qfl[g][0] = *(const bhalf8*)(&L[qrow + quad * 8]);
    qfl[g][1] = *(const bhalf8*)(&L[qrow + 32 + quad * 8]);
  }

  f32x4 acc_o[2][4] = {};
  float lpart[2][4] = {};

  uint4 sk0, sk1, sv0, sv1;            // staging regs
  int mcur[4], mnext[4];

  auto pref = [&](int kt) {
    sk0 = *(const uint4*)(&H[(size_t)(b * kN + kt + row0) * k3C + kC + h * kD + col0]);
    sk1 = *(const uint4*)(&H[(size_t)(b * kN + kt + row1) * k3C + kC + h * kD + col1]);
    sv0 = *(const uint4*)(&VTH[((size_t)bh * kD + row0) * kN + kt + col0]);
    sv1 = *(const uint4*)(&VTH[((size_t)bh * kD + row1) * kN + kt + col1]);
  };
  auto loadM = [&](int kt, int* m) {
    #pragma unroll
    for (int nt = 0; nt < 4; ++nt) m[nt] = mask[b * kN + kt + nt * 16 + l16];
  };

  pref(0);
  loadM(0, mcur);

  for (int i = 0; i < 32; ++i) {
    const int kt = i * 64;
    // drain staged regs into LDS
    *(uint4*)(&KtH[row0 * P + col0]) = sk0;
    *(uint4*)(&KtH[row1 * P + col1]) = sk1;
    *(uint4*)(&VtH[row0 * P + col0]) = sv0;
    *(uint4*)(&VtH[row1 * P + col1]) = sv1;
    __syncthreads();

    // issue next tile's global loads early; consumed next iter
    if (i < 31) { pref(kt + 64); loadM(kt + 64, mnext); }

    // S = (Qh+Ql)Kh ; p = flag*exp(s) -> Pt (C-layout -> A-layout)
    #pragma unroll
    for (int nt = 0; nt < 4; ++nt) {
      const int kr = (nt * 16 + l16) * P + quad * 8;
      const bhalf8 kh0 = *(const bhalf8*)(&KtH[kr]);
      const bhalf8 kh1 = *(const bhalf8*)(&KtH[kr + 32]);
      const float flag = mcur[nt] ? 1.0f : 0.0f;
      #pragma unroll
      for (int g = 0; g < 2; ++g) {
        f32x4 s = {};
        s = __builtin_amdgcn_mfma_f32_16x16x32_bf16(qfh[g][0], kh0, s, 0, 0, 0);
        s = __builtin_amdgcn_mfma_f32_16x16x32_bf16(qfh[g][1], kh1, s, 0, 0, 0);
        s = __builtin_amdgcn_mfma_f32_16x16x32_bf16(qfl[g][0], kh0, s, 0, 0, 0);
        s = __builtin_amdgcn_mfma_f32_16x16x32_bf16(qfl[g][1], kh1, s, 0, 0, 0);
        #pragma unroll
        for (int r = 0; r < 4; ++r) {
          const float p = flag * __expf(s[r]);   // s in [-8.02, 8.02]
          lpart[g][r] += p;
          Pt[wave][(g * 16 + quad * 4 + r) * P + nt * 16 + l16] = f2bf(p);
        }
      }
    }

    // O += P * Vh  (Pt per-wave: same-wave DS ordering, no barrier needed)
    #pragma unroll
    for (int kk = 0; kk < 2; ++kk) {
      const bhalf8 pa0 = *(const bhalf8*)(&Pt[wave][l16 * P + kk * 32 + quad * 8]);
      const bhalf8 pa1 = *(const bhalf8*)(&Pt[wave][(16 + l16) * P + kk * 32 + quad * 8]);
      #pragma unroll
      for (int dt = 0; dt < 4; ++dt) {
        const bhalf8 vb = *(const bhalf8*)(&VtH[(dt * 16 + l16) * P + kk * 32 + quad * 8]);
        acc_o[0][dt] = __builtin_amdgcn_mfma_f32_16x16x32_bf16(pa0, vb, acc_o[0][dt], 0, 0, 0);
        acc_o[1][dt] = __builtin_amdgcn_mfma_f32_16x16x32_bf16(pa1, vb, acc_o[1][dt], 0, 0, 0);
      }
    }

    #pragma unroll
    for (int nt = 0; nt < 4; ++nt) mcur[nt] = mnext[nt];
    __syncthreads();     // Kt/Vt readers done; next iter may overwrite
  }

  // final l reduction + normalize + store hi/lo into q-slice
  #pragma unroll
  for (int g = 0; g < 2; ++g)
    #pragma unroll
    for (int r = 0; r < 4; ++r) {
      float s = lpart[g][r];
      #pragma unroll
      for (int d = 1; d < 16; d <<= 1) s += __shfl_xor(s, d, 64);
      lpart[g][r] = s;
    }
  #pragma unroll
  for (int g = 0; g < 2; ++g)
    #pragma unroll
    for (int dt = 0; dt < 4; ++dt)
      #pragma unroll
      for (int r = 0; r < 4; ++r) {
        const int qrow = q0 + g * 16 + quad * 4 + r;
        const float inv = 1.0f / fmaxf(lpart[g][r], 1.0e-30f);
        const size_t off = (size_t)(b * kN + qrow) * k3C + h * kD + dt * 16 + l16;
        unsigned short hh, ll;
        split2(acc_o[g][dt][r] * inv, hh, ll);
        H[off] = hh; L[off] = ll;
      }
}

} // anonymous namespace

extern "C" void kernel_launch(void* const* d_in, const int* in_sizes, int n_in,
                              void* d_out, int out_size, void* d_ws, size_t ws_size,
                              hipStream_t stream)
{
  const float* x      = (const float*)d_in[0];
  const int*   maskp  = (const int*)d_in[1];
  const float* qkv_w  = (const float*)d_in[2];
  const float* qkv_b  = (const float*)d_in[3];
  const float* proj_w = (const float*)d_in[4];
  const float* proj_b = (const float*)d_in[5];
  const float* qn_w   = (const float*)d_in[6];
  const float* kn_w   = (const float*)d_in[7];
  float* out = (float*)d_out;

  unsigned short* qH = (unsigned short*)d_ws;      // qkv hi plane
  unsigned short* qL = qH + kPS;                   // qkv lo plane
  unsigned short* R1 = qL + kPS;                   // x planes -> later VT plane
  unsigned short* R2 = R1 + 2 * kXE;               // qkv_w planes -> later proj_w planes
  unsigned short* xH = R1,  *xL = R1 + kXE;
  unsigned short* VTH = R1;                        // reuse after gemm1
  unsigned short* wqH = R2, *wqL = R2 + kWQ;
  unsigned short* wpH = R2, *wpL = R2 + kWP;

  split_planes<<<(int)(kXE / 4 / 256), 256, 0, stream>>>(x, xH, xL, (int)(kXE / 4));
  split_planes<<<(int)(kWQ / 4 / 256), 256, 0, stream>>>(qkv_w, wqH, wqL, (int)(kWQ / 4));

  // 1) qkv = x @ qkv_w^T + qkv_b, RMSNorm(q,k) fused; lo written for q only
  gemm_planes<false, true><<<dim3(kTok / 128, k3C / 128), 256, 0, stream>>>(
      xH, xL, kC, wqH, wqL, qkv_b, nullptr, qH, qL, qn_w, kn_w, k3C, kC);

  // 2) pre-transpose V hi (overwrites x planes); pre-split proj_w
  vt_transpose<<<2048, 256, 0, stream>>>(qH, VTH);
  split_planes<<<(int)(kWP / 4 / 256), 256, 0, stream>>>(proj_w, wpH, wpL, (int)(kWP / 4));

  // 3) masked flash attention (XCD-swizzled 1-D grid)
  attn_kernel<<<dim3(512), 256, 0, stream>>>(qH, qL, VTH, maskp);

  // 4) out = attn @ proj_w^T + proj_b
  gemm_planes<true, false><<<dim3(kTok / 128, kC / 128), 256, 0, stream>>>(
      qH, qL, k3C, wpH, wpL, proj_b, out, nullptr, nullptr, nullptr, nullptr, kC, kC);
}

// Round 11
// 312.585 us; speedup vs baseline: 1.6124x; 1.4124x over previous
//
#include <hip/hip_runtime.h>
#include <hip/hip_bf16.h>
#include <stdint.h>

namespace {

constexpr int kB = 2;
constexpr int kN = 2048;
constexpr int kC = 1024;
constexpr int kH = 16;
constexpr int kD = 64;
constexpr int kTok = kB * kN;               // 4096
constexpr int k3C  = 3 * kC;                // 3072
constexpr size_t kPS = (size_t)kTok * k3C;  // qkv plane elems
constexpr size_t kXE = (size_t)kTok * kC;   // x / VT plane elems
constexpr size_t kWQ = (size_t)k3C * kC;    // qkv_w elems
constexpr size_t kWP = (size_t)kC * kC;     // proj_w elems

using bhalf8 = __attribute__((ext_vector_type(8))) __bf16;
using f32x4  = __attribute__((ext_vector_type(4))) float;

__device__ inline unsigned short f2bf(float f) {
  __hip_bfloat16 h = __float2bfloat16(f);
  return *reinterpret_cast<unsigned short*>(&h);
}
__device__ inline float bf2f(unsigned short u) {
  __hip_bfloat16 h;
  *reinterpret_cast<unsigned short*>(&h) = u;
  return __bfloat162float(h);
}
__device__ inline void split2(float v, unsigned short& h, unsigned short& l) {
  const unsigned short hb = f2bf(v);
  h = hb;
  l = f2bf(v - bf2f(hb));
}

// async global->LDS, 16B per lane; LDS dest must be wave-uniform base + lane*16
__device__ inline void glds16(const unsigned short* g, unsigned short* l) {
  __builtin_amdgcn_global_load_lds(
      (const __attribute__((address_space(1))) void*)g,
      (__attribute__((address_space(3))) void*)l, 16, 0, 0);
}

// ---- split fp32 -> bf16 hi/lo planes ----
__global__ __launch_bounds__(256)
void split_planes(const float* __restrict__ src,
                  unsigned short* __restrict__ H,
                  unsigned short* __restrict__ L, int n4)
{
  const int i = blockIdx.x * 256 + threadIdx.x;
  if (i >= n4) return;
  const float4 v = ((const float4*)src)[i];
  ushort4 hh, ll;
  split2(v.x, hh.x, ll.x); split2(v.y, hh.y, ll.y);
  split2(v.z, hh.z, ll.z); split2(v.w, hh.w, ll.w);
  ((ushort4*)H)[i] = hh;
  ((ushort4*)L)[i] = ll;
}

// ---- pre-transpose V (hi plane only) into VT[bh][d][token] ----
__global__ __launch_bounds__(256)
void vt_transpose(const unsigned short* __restrict__ H,
                  unsigned short* __restrict__ VTH)
{
  const int gw   = blockIdx.x * 4 + (threadIdx.x >> 6);  // 0..8191
  const int lane = threadIdx.x & 63;                     // = d
  const int bh   = gw >> 8;
  const int oct  = gw & 255;
  const int b = bh >> 4, h = bh & 15;
  const int tok0 = oct * 8;
  union { unsigned short u[8]; uint4 v; } ph;
  #pragma unroll
  for (int e = 0; e < 8; ++e) {
    const size_t g = (size_t)(b * kN + tok0 + e) * k3C + 2 * kC + h * kD + lane;
    ph.u[e] = H[g];
  }
  *(uint4*)(&VTH[((size_t)bh * kD + lane) * kN + tok0]) = ph.v;
}

// ---- plane GEMM: C = (AH+AL) @ (WH+WL)^T + bias; 3-term MFMA; m97 staging ----
template<bool OUTF32, bool FUSE_NORM>
__global__ __launch_bounds__(256)
void gemm_planes(const unsigned short* __restrict__ AH,
                 const unsigned short* __restrict__ AL, int lda,
                 const unsigned short* __restrict__ WH,
                 const unsigned short* __restrict__ WL,
                 const float* __restrict__ bias,
                 float* __restrict__ OutF,
                 unsigned short* __restrict__ OutH,
                 unsigned short* __restrict__ OutL,
                 const float* __restrict__ qn,
                 const float* __restrict__ kn,
                 int Nn, int K)
{
  __shared__ __align__(16) unsigned short AsH[128 * 32], AsL[128 * 32];
  __shared__ __align__(16) unsigned short BsH[128 * 32], BsL[128 * 32];

  const int t    = threadIdx.x;
  const int wave = t >> 6;
  const int lane = t & 63;
  const int quad = lane >> 4;
  const int l16  = lane & 15;
  const int bm = blockIdx.x * 128;
  const int bn = blockIdx.y * 128;
  const int wm = (wave >> 1) * 64;
  const int wn = (wave & 1) * 64;

  f32x4 acc[4][4] = {};

  for (int k0 = 0; k0 < K; k0 += 32) {
    #pragma unroll
    for (int r = 0; r < 2; ++r) {
      const int c   = r * 256 + t;
      const int row = c >> 2;
      const int col = (c & 3) * 8;
      glds16(&AH[(size_t)(bm + row) * lda + k0 + col], &AsH[c * 8]);
      glds16(&AL[(size_t)(bm + row) * lda + k0 + col], &AsL[c * 8]);
      glds16(&WH[(size_t)(bn + row) * K + k0 + col], &BsH[c * 8]);
      glds16(&WL[(size_t)(bn + row) * K + k0 + col], &BsL[c * 8]);
    }
    __syncthreads();

    bhalf8 afh[4], afl[4], bgh[4], bgl[4];
    #pragma unroll
    for (int i = 0; i < 4; ++i) {
      afh[i] = *(const bhalf8*)(&AsH[(wm + i * 16 + l16) * 32 + quad * 8]);
      afl[i] = *(const bhalf8*)(&AsL[(wm + i * 16 + l16) * 32 + quad * 8]);
      bgh[i] = *(const bhalf8*)(&BsH[(wn + i * 16 + l16) * 32 + quad * 8]);
      bgl[i] = *(const bhalf8*)(&BsL[(wn + i * 16 + l16) * 32 + quad * 8]);
    }
    #pragma unroll
    for (int i = 0; i < 4; ++i)
      #pragma unroll
      for (int j = 0; j < 4; ++j) {
        f32x4 a = acc[i][j];
        a = __builtin_amdgcn_mfma_f32_16x16x32_bf16(afh[i], bgh[j], a, 0, 0, 0);
        a = __builtin_amdgcn_mfma_f32_16x16x32_bf16(afh[i], bgl[j], a, 0, 0, 0);
        a = __builtin_amdgcn_mfma_f32_16x16x32_bf16(afl[i], bgh[j], a, 0, 0, 0);
        acc[i][j] = a;
      }
    __syncthreads();
  }

  // epilogue: C/D layout col=lane&15, row=quad*4+reg
  float bv[4], wv[4];
  const int slice = FUSE_NORM ? (bn >> 10) : 0;   // 0=q,1=k,2=v
  const bool writeL = !FUSE_NORM || slice == 0;
  #pragma unroll
  for (int j = 0; j < 4; ++j) {
    bv[j] = bias[bn + wn + j * 16 + l16];
    if (FUSE_NORM && slice < 2)
      wv[j] = (slice ? kn : qn)[j * 16 + l16];    // d = j*16+l16
  }

  #pragma unroll
  for (int i = 0; i < 4; ++i) {
    float val[4][4];
    #pragma unroll
    for (int j = 0; j < 4; ++j)
      #pragma unroll
      for (int r = 0; r < 4; ++r)
        val[j][r] = acc[i][j][r] + bv[j];

    if (FUSE_NORM && slice < 2) {
      #pragma unroll
      for (int r = 0; r < 4; ++r) {
        float ss = val[0][r] * val[0][r];
        #pragma unroll
        for (int j = 1; j < 4; ++j) ss += val[j][r] * val[j][r];
        #pragma unroll
        for (int d = 1; d < 16; d <<= 1) ss += __shfl_xor(ss, d, 64);
        float rinv = rsqrtf(ss * (1.0f / 64.0f) + 1e-6f);
        if (slice == 0) rinv *= 0.125f;           // q * D^-0.5
        #pragma unroll
        for (int j = 0; j < 4; ++j) val[j][r] = wv[j] * (val[j][r] * rinv);
      }
    }

    #pragma unroll
    for (int j = 0; j < 4; ++j) {
      const int n = bn + wn + j * 16 + l16;
      #pragma unroll
      for (int r = 0; r < 4; ++r) {
        const int m = bm + wm + i * 16 + quad * 4 + r;
        if (OUTF32) {
          OutF[(size_t)m * Nn + n] = val[j][r];
        } else {
          unsigned short hh, ll;
          split2(val[j][r], hh, ll);
          OutH[(size_t)m * Nn + n] = hh;
          if (writeL) OutL[(size_t)m * Nn + n] = ll;
        }
      }
    }
  }
}

// ---- flash attention v6: r10 kernel, spill fix (no min-waves pin) ----
// launch_bounds(256,4) in r9/r10 pinned VGPR=64 -> per-iter scratch spills
// (WRITE_SIZE 294 MB). Unpinned: compiler takes ~128+ VGPR, 2-3 blocks/CU.
__global__ __launch_bounds__(256)
void attn_kernel(unsigned short* __restrict__ H, unsigned short* __restrict__ L,
                 const unsigned short* __restrict__ VTH,
                 const int* __restrict__ mask)
{
  constexpr int P = 72;
  __shared__ __align__(16) unsigned short KtH[64 * P];   //  9.2 KB [key][d]
  __shared__ __align__(16) unsigned short VtH[64 * P];   //  9.2 KB [d][key]
  __shared__ __align__(16) unsigned short Pt[4][32 * P]; // 18.4 KB per-wave [q][key]

  const int t    = threadIdx.x;
  const int wave = t >> 6;
  const int lane = t & 63;
  const int quad = lane >> 4;
  const int l16  = lane & 15;

  // XCD swizzle: lin%8 = XCD (dispatch round-robin); 4 bh per XCD.
  const int lin  = blockIdx.x;          // 0..511
  const int xcd  = lin & 7;
  const int slot = lin >> 3;            // 0..63
  const int bh   = xcd + 8 * (slot >> 4);
  const int qblk = slot & 15;
  const int b  = bh >> 4;
  const int h  = bh & 15;
  const int q0 = qblk * 128 + wave * 32;  // 32 q-rows/wave

  // staging geometry: 2 chunks of 8 u16 per thread per tile
  const int row0 = t >> 3,         col0 = (t & 7) * 8;
  const int row1 = (256 + t) >> 3, col1 = ((256 + t) & 7) * 8;

  // Q fragments, both groups (A-layout: m=l16, k=quad*8+j)
  bhalf8 qfh[2][2], qfl[2][2];
  #pragma unroll
  for (int g = 0; g < 2; ++g) {
    const size_t qrow = (size_t)(b * kN + q0 + g * 16 + l16) * k3C + h * kD;
    qfh[g][0] = *(const bhalf8*)(&H[qrow + quad * 8]);
    qfh[g][1] = *(const bhalf8*)(&H[qrow + 32 + quad * 8]);
    qfl[g][0] = *(const bhalf8*)(&L[qrow + quad * 8]);
    qfl[g][1] = *(const bhalf8*)(&L[qrow + 32 + quad * 8]);
  }

  f32x4 acc_o[2][4] = {};
  float lpart[2][4] = {};

  uint4 sk0, sk1, sv0, sv1;            // staging regs
  int mcur[4], mnext[4];

  auto pref = [&](int kt) {
    sk0 = *(const uint4*)(&H[(size_t)(b * kN + kt + row0) * k3C + kC + h * kD + col0]);
    sk1 = *(const uint4*)(&H[(size_t)(b * kN + kt + row1) * k3C + kC + h * kD + col1]);
    sv0 = *(const uint4*)(&VTH[((size_t)bh * kD + row0) * kN + kt + col0]);
    sv1 = *(const uint4*)(&VTH[((size_t)bh * kD + row1) * kN + kt + col1]);
  };
  auto loadM = [&](int kt, int* m) {
    #pragma unroll
    for (int nt = 0; nt < 4; ++nt) m[nt] = mask[b * kN + kt + nt * 16 + l16];
  };

  pref(0);
  loadM(0, mcur);

  for (int i = 0; i < 32; ++i) {
    const int kt = i * 64;
    // drain staged regs into LDS
    *(uint4*)(&KtH[row0 * P + col0]) = sk0;
    *(uint4*)(&KtH[row1 * P + col1]) = sk1;
    *(uint4*)(&VtH[row0 * P + col0]) = sv0;
    *(uint4*)(&VtH[row1 * P + col1]) = sv1;
    __syncthreads();

    // issue next tile's global loads early; consumed next iter
    if (i < 31) { pref(kt + 64); loadM(kt + 64, mnext); }

    // S = (Qh+Ql)Kh ; p = flag*exp(s) -> Pt (C-layout -> A-layout)
    #pragma unroll
    for (int nt = 0; nt < 4; ++nt) {
      const int kr = (nt * 16 + l16) * P + quad * 8;
      const bhalf8 kh0 = *(const bhalf8*)(&KtH[kr]);
      const bhalf8 kh1 = *(const bhalf8*)(&KtH[kr + 32]);
      const float flag = mcur[nt] ? 1.0f : 0.0f;
      #pragma unroll
      for (int g = 0; g < 2; ++g) {
        f32x4 s = {};
        s = __builtin_amdgcn_mfma_f32_16x16x32_bf16(qfh[g][0], kh0, s, 0, 0, 0);
        s = __builtin_amdgcn_mfma_f32_16x16x32_bf16(qfh[g][1], kh1, s, 0, 0, 0);
        s = __builtin_amdgcn_mfma_f32_16x16x32_bf16(qfl[g][0], kh0, s, 0, 0, 0);
        s = __builtin_amdgcn_mfma_f32_16x16x32_bf16(qfl[g][1], kh1, s, 0, 0, 0);
        #pragma unroll
        for (int r = 0; r < 4; ++r) {
          const float p = flag * __expf(s[r]);   // s in [-8.02, 8.02]
          lpart[g][r] += p;
          Pt[wave][(g * 16 + quad * 4 + r) * P + nt * 16 + l16] = f2bf(p);
        }
      }
    }

    // O += P * Vh  (Pt per-wave: same-wave DS ordering, no barrier needed)
    #pragma unroll
    for (int kk = 0; kk < 2; ++kk) {
      const bhalf8 pa0 = *(const bhalf8*)(&Pt[wave][l16 * P + kk * 32 + quad * 8]);
      const bhalf8 pa1 = *(const bhalf8*)(&Pt[wave][(16 + l16) * P + kk * 32 + quad * 8]);
      #pragma unroll
      for (int dt = 0; dt < 4; ++dt) {
        const bhalf8 vb = *(const bhalf8*)(&VtH[(dt * 16 + l16) * P + kk * 32 + quad * 8]);
        acc_o[0][dt] = __builtin_amdgcn_mfma_f32_16x16x32_bf16(pa0, vb, acc_o[0][dt], 0, 0, 0);
        acc_o[1][dt] = __builtin_amdgcn_mfma_f32_16x16x32_bf16(pa1, vb, acc_o[1][dt], 0, 0, 0);
      }
    }

    #pragma unroll
    for (int nt = 0; nt < 4; ++nt) mcur[nt] = mnext[nt];
    __syncthreads();     // Kt/Vt readers done; next iter may overwrite
  }

  // final l reduction + normalize + store hi/lo into q-slice
  #pragma unroll
  for (int g = 0; g < 2; ++g)
    #pragma unroll
    for (int r = 0; r < 4; ++r) {
      float s = lpart[g][r];
      #pragma unroll
      for (int d = 1; d < 16; d <<= 1) s += __shfl_xor(s, d, 64);
      lpart[g][r] = s;
    }
  #pragma unroll
  for (int g = 0; g < 2; ++g)
    #pragma unroll
    for (int dt = 0; dt < 4; ++dt)
      #pragma unroll
      for (int r = 0; r < 4; ++r) {
        const int qrow = q0 + g * 16 + quad * 4 + r;
        const float inv = 1.0f / fmaxf(lpart[g][r], 1.0e-30f);
        const size_t off = (size_t)(b * kN + qrow) * k3C + h * kD + dt * 16 + l16;
        unsigned short hh, ll;
        split2(acc_o[g][dt][r] * inv, hh, ll);
        H[off] = hh; L[off] = ll;
      }
}

} // anonymous namespace

extern "C" void kernel_launch(void* const* d_in, const int* in_sizes, int n_in,
                              void* d_out, int out_size, void* d_ws, size_t ws_size,
                              hipStream_t stream)
{
  const float* x      = (const float*)d_in[0];
  const int*   maskp  = (const int*)d_in[1];
  const float* qkv_w  = (const float*)d_in[2];
  const float* qkv_b  = (const float*)d_in[3];
  const float* proj_w = (const float*)d_in[4];
  const float* proj_b = (const float*)d_in[5];
  const float* qn_w   = (const float*)d_in[6];
  const float* kn_w   = (const float*)d_in[7];
  float* out = (float*)d_out;

  unsigned short* qH = (unsigned short*)d_ws;      // qkv hi plane
  unsigned short* qL = qH + kPS;                   // qkv lo plane
  unsigned short* R1 = qL + kPS;                   // x planes -> later VT plane
  unsigned short* R2 = R1 + 2 * kXE;               // qkv_w planes -> later proj_w planes
  unsigned short* xH = R1,  *xL = R1 + kXE;
  unsigned short* VTH = R1;                        // reuse after gemm1
  unsigned short* wqH = R2, *wqL = R2 + kWQ;
  unsigned short* wpH = R2, *wpL = R2 + kWP;

  split_planes<<<(int)(kXE / 4 / 256), 256, 0, stream>>>(x, xH, xL, (int)(kXE / 4));
  split_planes<<<(int)(kWQ / 4 / 256), 256, 0, stream>>>(qkv_w, wqH, wqL, (int)(kWQ / 4));

  // 1) qkv = x @ qkv_w^T + qkv_b, RMSNorm(q,k) fused; lo written for q only
  gemm_planes<false, true><<<dim3(kTok / 128, k3C / 128), 256, 0, stream>>>(
      xH, xL, kC, wqH, wqL, qkv_b, nullptr, qH, qL, qn_w, kn_w, k3C, kC);

  // 2) pre-transpose V hi (overwrites x planes); pre-split proj_w
  vt_transpose<<<2048, 256, 0, stream>>>(qH, VTH);
  split_planes<<<(int)(kWP / 4 / 256), 256, 0, stream>>>(proj_w, wpH, wpL, (int)(kWP / 4));

  // 3) masked flash attention (XCD-swizzled 1-D grid)
  attn_kernel<<<dim3(512), 256, 0, stream>>>(qH, qL, VTH, maskp);

  // 4) out = attn @ proj_w^T + proj_b
  gemm_planes<true, false><<<dim3(kTok / 128, kC / 128), 256, 0, stream>>>(
      qH, qL, k3C, wpH, wpL, proj_b, out, nullptr, nullptr, nullptr, nullptr, kC, kC);
}